// Round 3
// baseline (1267.016 us; speedup 1.0000x reference)
//
#include <hip/hip_runtime.h>
#include <cstdint>
#include <cstddef>

#define WS_ 8
#define DIM_ 192
#define HEADS_ 6
#define HD_ 32
#define HH_ 56
#define NW_ 7
#define NWIN_ 49
#define LTOK_ 3136
#define NTOK_ 200704
#define NWTOT_ 3136
#define SHIFT_ 4
#define SCALE_ 0.17677669529663687f

typedef unsigned short ushort_t;
typedef __attribute__((ext_vector_type(8))) short short8;
typedef __attribute__((ext_vector_type(4))) short bf16x4;
typedef __attribute__((ext_vector_type(4))) float floatx4;
typedef __attribute__((ext_vector_type(8))) unsigned short ushort8;

__device__ __forceinline__ float b2f(ushort_t u) {
    union { unsigned int i; float f; } c; c.i = ((unsigned int)u) << 16; return c.f;
}
__device__ __forceinline__ ushort_t f2b(float f) {
    union { float f; unsigned int i; } c; c.f = f;
    unsigned int u = c.i;
    unsigned int r = (u + 0x7FFFu + ((u >> 16) & 1u)) >> 16;
    return (ushort_t)r;
}

__device__ __forceinline__ void load_lds16(const void* g, void* l) {
    __builtin_amdgcn_global_load_lds(
        (const __attribute__((address_space(1))) unsigned int*)g,
        (__attribute__((address_space(3))) unsigned int*)l, 16, 0, 0);
}

// global window-token row r (win*64 + n) -> image token index, incl. roll.
__device__ __forceinline__ int win_row_to_img(int r) {
    int win = r >> 6, n = r & 63;
    int b = win / NWIN_, wI = win - b * NWIN_;
    int wh = wI / NW_, wwi = wI - wh * NW_;
    int i = n >> 3, j = n & 7;
    int hh = wh * WS_ + i + SHIFT_; if (hh >= HH_) hh -= HH_;
    int ww = wwi * WS_ + j + SHIFT_; if (ww >= HH_) ww -= HH_;
    return b * LTOK_ + hh * HH_ + ww;
}

// f32 weight [K][N] -> bf16 transposed [N][K]
__global__ void transpose_kernel(const float* __restrict__ in,
                                 ushort_t* __restrict__ out, int K, int N) {
    int id = blockIdx.x * 256 + threadIdx.x;
    if (id >= K * N) return;
    int k = id / N, n = id - k * N;
    out[(size_t)n * K + k] = f2b(in[id]);
}

// Precompute Spre[type][head][q][k] = rpb bias + shift mask.
__global__ void bias_kernel(const float* __restrict__ rpb, float* __restrict__ Spre) {
    int th = blockIdx.x;                 // 0..23 = type*6 + head
    int type = th / HEADS_, head = th - type * HEADS_;
    for (int idx = threadIdx.x; idx < 4096; idx += 256) {
        int q = idx >> 6, k = idx & 63;
        int i1 = q >> 3, j1 = q & 7, i2 = k >> 3, j2 = k & 7;
        int rel = (i1 - i2 + 7) * 15 + (j1 - j2 + 7);
        float v = rpb[rel * HEADS_ + head];
        int rh1 = (type & 2) ? (i1 < 4 ? 1 : 2) : 0;
        int rw1 = (type & 1) ? (j1 < 4 ? 1 : 2) : 0;
        int rh2 = (type & 2) ? (i2 < 4 ? 1 : 2) : 0;
        int rw2 = (type & 1) ? (j2 < 4 ? 1 : 2) : 0;
        if (rh1 != rh2 || rw1 != rw2) v -= 100.0f;
        Spre[(size_t)th * 4096 + idx] = v;
    }
}

// One wave per token; lane covers cols {l, l+64, l+128}. f32 in, bf16 out.
template <bool PERMUTE>
__global__ __launch_bounds__(256) void ln_kernel(const float* __restrict__ xin,
                                                 const float* __restrict__ w,
                                                 const float* __restrict__ bia,
                                                 ushort_t* __restrict__ out,
                                                 int rowOff) {
    int t = blockIdx.x * 4 + (threadIdx.x >> 6);
    int lane = threadIdx.x & 63;
    int src = PERMUTE ? win_row_to_img(rowOff + t) : t;
    const float* xp = xin + (size_t)src * DIM_;
    float v0 = xp[lane];
    float v1 = xp[lane + 64];
    float v2 = xp[lane + 128];
    float s = v0 + v1 + v2;
    float ss = v0 * v0 + v1 * v1 + v2 * v2;
#pragma unroll
    for (int o = 32; o > 0; o >>= 1) {
        s += __shfl_xor(s, o);
        ss += __shfl_xor(ss, o);
    }
    float mu = s * (1.0f / 192.0f);
    float var = ss * (1.0f / 192.0f) - mu * mu;
    float inv = rsqrtf(var + 1e-5f);
    ushort_t* op = out + (size_t)t * DIM_;
    op[lane]       = f2b((v0 - mu) * inv * w[lane]       + bia[lane]);
    op[lane + 64]  = f2b((v1 - mu) * inv * w[lane + 64]  + bia[lane + 64]);
    op[lane + 128] = f2b((v2 - mu) * inv * w[lane + 128] + bia[lane + 128]);
}

#define EPI_STORE 0
#define EPI_GELU 1
#define EPI_PROJ 2
#define EPI_FC2 3
#define EPI_QKV 4

// LDS-staged GEMM: C[M,N] = A[M,K] @ W[K,N] + bias; A,Bt bf16; bias f32.
template <int EPI>
__global__ __launch_bounds__(256) void gemm_kernel(const ushort_t* __restrict__ A,
                                                   const ushort_t* __restrict__ Bt,
                                                   const float* __restrict__ bias,
                                                   void* __restrict__ outv,
                                                   const float* __restrict__ aux,
                                                   int K, int N, int rowOff) {
    __shared__ char smem[40960];  // A: 2 x 8192, B: 2 x 12288

    int tid = threadIdx.x;
    int wave = tid >> 6, lane = tid & 63;
    int quad = lane >> 4, l16 = lane & 15;
    int wave_r = wave >> 1, wave_c = wave & 1;   // 2x2 wave grid
    int row0 = blockIdx.x * 128;
    int n0 = blockIdx.y * 192;

    floatx4 acc[4][6];
#pragma unroll
    for (int rt = 0; rt < 4; ++rt)
#pragma unroll
        for (int ct = 0; ct < 6; ++ct)
#pragma unroll
            for (int e = 0; e < 4; ++e) acc[rt][ct][e] = 0.0f;

    int nk = K >> 5;

    auto stage = [&](int kk, int buf) {
#pragma unroll
        for (int j = 0; j < 2; ++j) {
            int o = (tid + j * 256) * 16;
            int row = o >> 6, kb = o & 63;
            const ushort_t* g = A + (size_t)(row0 + row) * K + kk * 32 + (kb >> 1);
            load_lds16(g, smem + buf * 8192 + o);
        }
#pragma unroll
        for (int j = 0; j < 3; ++j) {
            int o = (tid + j * 256) * 16;
            int row = o >> 6, kb = o & 63;
            const ushort_t* g = Bt + (size_t)(n0 + row) * K + kk * 32 + (kb >> 1);
            load_lds16(g, smem + 16384 + buf * 12288 + o);
        }
    };

    stage(0, 0);
    for (int kk = 0; kk < nk; ++kk) {
        int cur = kk & 1;
        __syncthreads();
        if (kk + 1 < nk) stage(kk + 1, cur ^ 1);

        short8 a[4];
#pragma unroll
        for (int rt = 0; rt < 4; ++rt)
            a[rt] = *(const short8*)(smem + cur * 8192 +
                     ((wave_r * 64 + rt * 16 + l16) * 64 + quad * 16));
#pragma unroll
        for (int ct = 0; ct < 6; ++ct) {
            short8 b = *(const short8*)(smem + 16384 + cur * 12288 +
                        ((wave_c * 96 + ct * 16 + l16) * 64 + quad * 16));
#pragma unroll
            for (int rt = 0; rt < 4; ++rt)
                acc[rt][ct] = __builtin_amdgcn_mfma_f32_16x16x32_bf16(a[rt], b, acc[rt][ct], 0, 0, 0);
        }
    }

#pragma unroll
    for (int ct = 0; ct < 6; ++ct) {
        int c = n0 + wave_c * 96 + ct * 16 + l16;
        float bs = bias[c];
#pragma unroll
        for (int rt = 0; rt < 4; ++rt) {
#pragma unroll
            for (int r = 0; r < 4; ++r) {
                int rr = row0 + wave_r * 64 + rt * 16 + quad * 4 + r;
                float val = acc[rt][ct][r] + bs;
                if (EPI == EPI_STORE) {
                    ((ushort_t*)outv)[(size_t)rr * N + c] = f2b(val);
                } else if (EPI == EPI_QKV) {
                    float sv = (c < DIM_) ? val * SCALE_ : val;
                    ((ushort_t*)outv)[(size_t)rr * N + c] = f2b(sv);
                } else if (EPI == EPI_GELU) {
                    float g = 0.5f * val * (1.0f + erff(val * 0.70710678118654752f));
                    ((ushort_t*)outv)[(size_t)rr * N + c] = f2b(g);
                } else if (EPI == EPI_PROJ) {
                    int dst = win_row_to_img(rowOff + rr);
                    size_t idx = (size_t)dst * DIM_ + c;
                    ((float*)outv)[idx] = val + aux[idx];
                } else {  // EPI_FC2
                    size_t idx = (size_t)rr * DIM_ + c;
                    ((float*)outv)[idx] = val + aux[idx];
                }
            }
        }
    }
}

// MFMA attention: one wave per (window, head). 4 waves/block, wave-private LDS.
__global__ __launch_bounds__(256) void attn_kernel(const ushort_t* __restrict__ qkv,
                                                   const float* __restrict__ Spre,
                                                   ushort_t* __restrict__ aout,
                                                   int win0, int nwh) {
    __shared__ char smem[32768];
    int wave = threadIdx.x >> 6;
    int whid = blockIdx.x * 4 + wave;
    if (whid >= nwh) return;
    int lane = threadIdx.x & 63;
    int l16 = lane & 15, quad = lane >> 4;
    int winl = whid / HEADS_, head = whid - winl * HEADS_;
    int wI = (win0 + winl) % NWIN_;
    int wh = wI / NW_, wwi = wI - wh * NW_;
    int type = ((wh == 6) ? 2 : 0) + ((wwi == 6) ? 1 : 0);

    const ushort_t* qb = qkv + (size_t)(winl * 64) * 576 + head * HD_;

    short8 vfrag[2][2];
#pragma unroll
    for (int kk = 0; kk < 2; ++kk)
#pragma unroll
        for (int dt = 0; dt < 2; ++dt)
#pragma unroll
            for (int e = 0; e < 8; ++e)
                vfrag[dt][kk][e] =
                    (short)qb[(size_t)(kk * 32 + quad * 8 + e) * 576 + 2 * DIM_ + dt * 16 + l16];

    short8 kf[4], qf[4];
#pragma unroll
    for (int t = 0; t < 4; ++t) {
        kf[t] = *(const short8*)(qb + (size_t)(t * 16 + l16) * 576 + DIM_ + quad * 8);
        qf[t] = *(const short8*)(qb + (size_t)(t * 16 + l16) * 576 + quad * 8);
    }

    const float* bp = Spre + (size_t)(type * HEADS_ + head) * 4096;
    floatx4 acc[4][4];
#pragma unroll
    for (int art = 0; art < 4; ++art)
#pragma unroll
        for (int act = 0; act < 4; ++act)
            acc[art][act] = *(const floatx4*)(bp + (act * 16 + l16) * 64 + art * 16 + quad * 4);

#pragma unroll
    for (int art = 0; art < 4; ++art)
#pragma unroll
        for (int act = 0; act < 4; ++act)
            acc[art][act] = __builtin_amdgcn_mfma_f32_16x16x32_bf16(
                kf[art], qf[act], acc[art][act], 0, 0, 0);

    char* pb = smem + wave * 8192;
    int sw = (l16 & 7) << 4;
#pragma unroll
    for (int act = 0; act < 4; ++act) {
        float m = -1e30f;
#pragma unroll
        for (int art = 0; art < 4; ++art)
#pragma unroll
            for (int r = 0; r < 4; ++r) m = fmaxf(m, acc[art][act][r]);
        m = fmaxf(m, __shfl_xor(m, 16));
        m = fmaxf(m, __shfl_xor(m, 32));
        float s = 0.0f;
#pragma unroll
        for (int art = 0; art < 4; ++art)
#pragma unroll
            for (int r = 0; r < 4; ++r) {
                float e = __expf(acc[art][act][r] - m);
                acc[art][act][r] = e;
                s += e;
            }
        s += __shfl_xor(s, 16);
        s += __shfl_xor(s, 32);
        float inv = 1.0f / s;
        int q = act * 16 + l16;
        char* rowp = pb + q * 128;
#pragma unroll
        for (int art = 0; art < 4; ++art) {
            bf16x4 pk4;
#pragma unroll
            for (int r = 0; r < 4; ++r) pk4[r] = (short)f2b(acc[art][act][r] * inv);
            *(bf16x4*)(rowp + ((art * 32 + quad * 8) ^ sw)) = pk4;
        }
    }

    floatx4 accO[4][2];
#pragma unroll
    for (int ot = 0; ot < 4; ++ot)
#pragma unroll
        for (int dt = 0; dt < 2; ++dt)
#pragma unroll
            for (int e = 0; e < 4; ++e) accO[ot][dt][e] = 0.0f;
#pragma unroll
    for (int kk = 0; kk < 2; ++kk) {
        short8 pa[4];
#pragma unroll
        for (int ot = 0; ot < 4; ++ot)
            pa[ot] = *(const short8*)(pb + (ot * 16 + l16) * 128 +
                                      ((kk * 64 + quad * 16) ^ sw));
#pragma unroll
        for (int dt = 0; dt < 2; ++dt)
#pragma unroll
            for (int ot = 0; ot < 4; ++ot)
                accO[ot][dt] = __builtin_amdgcn_mfma_f32_16x16x32_bf16(
                    pa[ot], vfrag[dt][kk], accO[ot][dt], 0, 0, 0);
    }

    ushort_t* op = aout + (size_t)(winl * 64) * DIM_ + head * HD_;
#pragma unroll
    for (int ot = 0; ot < 4; ++ot)
#pragma unroll
        for (int dt = 0; dt < 2; ++dt)
#pragma unroll
            for (int r = 0; r < 4; ++r)
                op[(size_t)(ot * 16 + quad * 4 + r) * DIM_ + dt * 16 + l16] =
                    f2b(accO[ot][dt][r]);
}

// Fused LN2 + fc1 + GELU + fc2 + residual. One block = 64 tokens, 4 waves.
// As: [64][192] bf16 (LN output), Hs: [64][384] bf16 (half of h), both
// XOR-swizzled (byte ^= (row&7)<<4 within row) to kill ds_read_b128 conflicts.
// W1t/W2t B-fragments stream from global (L2-resident, 0.6 MB total).
__global__ __launch_bounds__(256) void mlp_kernel(const float* __restrict__ x1,
                                                  const float* __restrict__ lnw,
                                                  const float* __restrict__ lnb,
                                                  const ushort_t* __restrict__ w1t,
                                                  const float* __restrict__ b1,
                                                  const ushort_t* __restrict__ w2t,
                                                  const float* __restrict__ b2,
                                                  float* __restrict__ out) {
    __shared__ char smem[24576 + 49152];
    char* As = smem;
    char* Hs = smem + 24576;
    int tid = threadIdx.x;
    int wave = tid >> 6, lane = tid & 63;
    int quad = lane >> 4, l16 = lane & 15;
    int row0 = blockIdx.x * 64;

    // ---- LN2: each wave handles rows wave, wave+4, ..., wave+60
    {
        float wa = lnw[lane], wb = lnw[lane + 64], wc2 = lnw[lane + 128];
        float ba = lnb[lane], bb = lnb[lane + 64], bc2 = lnb[lane + 128];
        for (int i = 0; i < 16; ++i) {
            int row = i * 4 + wave;
            const float* xp = x1 + (size_t)(row0 + row) * DIM_;
            float v0 = xp[lane], v1 = xp[lane + 64], v2 = xp[lane + 128];
            float s = v0 + v1 + v2;
            float ss = v0 * v0 + v1 * v1 + v2 * v2;
#pragma unroll
            for (int o = 32; o > 0; o >>= 1) {
                s += __shfl_xor(s, o);
                ss += __shfl_xor(ss, o);
            }
            float mu = s * (1.0f / 192.0f);
            float var = ss * (1.0f / 192.0f) - mu * mu;
            float inv = rsqrtf(var + 1e-5f);
            char* rp = As + row * 384;
            int sx = (row & 7) << 4;
            *(ushort_t*)(rp + ((lane * 2) ^ sx))         = f2b((v0 - mu) * inv * wa + ba);
            *(ushort_t*)(rp + (((lane + 64) * 2) ^ sx))  = f2b((v1 - mu) * inv * wb + bb);
            *(ushort_t*)(rp + (((lane + 128) * 2) ^ sx)) = f2b((v2 - mu) * inv * wc2 + bc2);
        }
    }
    __syncthreads();

    floatx4 acc2[4][3];
#pragma unroll
    for (int rt = 0; rt < 4; ++rt)
#pragma unroll
        for (int ct = 0; ct < 3; ++ct)
#pragma unroll
            for (int e = 0; e < 4; ++e) acc2[rt][ct][e] = 0.0f;

#pragma unroll
    for (int h = 0; h < 2; ++h) {
        // ---- fc1 half: per wave 96 cols, in two 48-col sub-chunks
#pragma unroll
        for (int sub = 0; sub < 2; ++sub) {
            floatx4 acc1[4][3];
#pragma unroll
            for (int rt = 0; rt < 4; ++rt)
#pragma unroll
                for (int ct = 0; ct < 3; ++ct)
#pragma unroll
                    for (int e = 0; e < 4; ++e) acc1[rt][ct][e] = 0.0f;
#pragma unroll
            for (int kk = 0; kk < 6; ++kk) {
                short8 a[4];
#pragma unroll
                for (int rt = 0; rt < 4; ++rt) {
                    int row = rt * 16 + l16;
                    a[rt] = *(const short8*)(As + row * 384 +
                             ((kk * 64 + quad * 16) ^ ((row & 7) << 4)));
                }
#pragma unroll
                for (int ct = 0; ct < 3; ++ct) {
                    int n = h * 384 + wave * 96 + sub * 48 + ct * 16 + l16;
                    short8 bfr = *(const short8*)(w1t + (size_t)n * 192 + kk * 32 + quad * 8);
#pragma unroll
                    for (int rt = 0; rt < 4; ++rt)
                        acc1[rt][ct] = __builtin_amdgcn_mfma_f32_16x16x32_bf16(
                            a[rt], bfr, acc1[rt][ct], 0, 0, 0);
                }
            }
            // gelu -> bf16 -> Hs
#pragma unroll
            for (int ct = 0; ct < 3; ++ct) {
                int colh = wave * 96 + sub * 48 + ct * 16 + l16;
                float bs = b1[h * 384 + colh];
#pragma unroll
                for (int rt = 0; rt < 4; ++rt) {
#pragma unroll
                    for (int r = 0; r < 4; ++r) {
                        int row = rt * 16 + quad * 4 + r;
                        float val = acc1[rt][ct][r] + bs;
                        float g = 0.5f * val * (1.0f + erff(val * 0.70710678118654752f));
                        *(ushort_t*)(Hs + row * 768 +
                                     ((colh * 2) ^ ((row & 7) << 4))) = f2b(g);
                    }
                }
            }
        }
        __syncthreads();
        // ---- fc2 partial over k-slice [h*384, h*384+384)
#pragma unroll
        for (int kk = 0; kk < 12; ++kk) {
            short8 a[4];
#pragma unroll
            for (int rt = 0; rt < 4; ++rt) {
                int row = rt * 16 + l16;
                a[rt] = *(const short8*)(Hs + row * 768 +
                         ((kk * 64 + quad * 16) ^ ((row & 7) << 4)));
            }
#pragma unroll
            for (int ct = 0; ct < 3; ++ct) {
                int n2 = wave * 48 + ct * 16 + l16;
                short8 bfr = *(const short8*)(w2t + (size_t)n2 * 768 +
                                              h * 384 + kk * 32 + quad * 8);
#pragma unroll
                for (int rt = 0; rt < 4; ++rt)
                    acc2[rt][ct] = __builtin_amdgcn_mfma_f32_16x16x32_bf16(
                        a[rt], bfr, acc2[rt][ct], 0, 0, 0);
            }
        }
        __syncthreads();   // Hs reuse for next half
    }

    // ---- epilogue: + bias + residual, f32 in-place
#pragma unroll
    for (int ct = 0; ct < 3; ++ct) {
        int c = wave * 48 + ct * 16 + l16;
        float bs = b2[c];
#pragma unroll
        for (int rt = 0; rt < 4; ++rt) {
#pragma unroll
            for (int r = 0; r < 4; ++r) {
                int rr = row0 + rt * 16 + quad * 4 + r;
                size_t idx = (size_t)rr * DIM_ + c;
                out[idx] = acc2[rt][ct][r] + bs + x1[idx];
            }
        }
    }
}

extern "C" void kernel_launch(void* const* d_in, const int* in_sizes, int n_in,
                              void* d_out, int out_size, void* d_ws, size_t ws_size,
                              hipStream_t stream) {
    const float* x      = (const float*)d_in[0];
    const float* ln1_w  = (const float*)d_in[1];
    const float* ln1_b  = (const float*)d_in[2];
    const float* qkv_w  = (const float*)d_in[3];
    const float* qkv_b  = (const float*)d_in[4];
    const float* proj_w = (const float*)d_in[5];
    const float* proj_b = (const float*)d_in[6];
    const float* rpb    = (const float*)d_in[7];
    const float* ln2_w  = (const float*)d_in[8];
    const float* ln2_b  = (const float*)d_in[9];
    const float* fc1_w  = (const float*)d_in[10];
    const float* fc1_b  = (const float*)d_in[11];
    const float* fc2_w  = (const float*)d_in[12];
    const float* fc2_b  = (const float*)d_in[13];

    char* ws = (char*)d_ws;
    size_t off = 0;
    auto alloc = [&](size_t bytes) -> void* {
        void* p = ws + off;
        off += (bytes + 255) & ~(size_t)255;
        return p;
    };
    ushort_t* qkv_wt  = (ushort_t*)alloc((size_t)576 * 192 * 2);
    ushort_t* proj_wt = (ushort_t*)alloc((size_t)192 * 192 * 2);
    ushort_t* fc1_wt  = (ushort_t*)alloc((size_t)768 * 192 * 2);
    ushort_t* fc2_wt  = (ushort_t*)alloc((size_t)192 * 768 * 2);
    float*    SpreT   = (float*)alloc((size_t)4 * HEADS_ * 4096 * sizeof(float));

    // x1 lives in d_out (f32; fully written by proj scatter before any read).
    float* x1 = (float*)d_out;

    size_t budget = (ws_size > off + 4096) ? (ws_size - off - 4096) : 0;
    long rows = (long)(budget / 1920);
    rows = (rows / 128) * 128;
    if (rows < 128) rows = 128;
    if (rows > NTOK_) rows = NTOK_;
    int chunkRows = (int)rows;
    int Wc = chunkRows / 64;            // even
    if (Wc > NWTOT_) Wc = NWTOT_;

    ushort_t* bufS = (ushort_t*)alloc((size_t)chunkRows * 192 * 2);  // xw / attn_out
    ushort_t* bufL = (ushort_t*)alloc((size_t)chunkRows * 768 * 2);  // qkv
    (void)n_in; (void)in_sizes; (void)out_size;

    transpose_kernel<<<(192 * 576 + 255) / 256, 256, 0, stream>>>(qkv_w, qkv_wt, 192, 576);
    transpose_kernel<<<(192 * 192 + 255) / 256, 256, 0, stream>>>(proj_w, proj_wt, 192, 192);
    transpose_kernel<<<(192 * 768 + 255) / 256, 256, 0, stream>>>(fc1_w, fc1_wt, 192, 768);
    transpose_kernel<<<(768 * 192 + 255) / 256, 256, 0, stream>>>(fc2_w, fc2_wt, 768, 192);
    bias_kernel<<<4 * HEADS_, 256, 0, stream>>>(rpb, SpreT);

    // ---- Phase A: LN1+roll+partition -> qkv(+scale q) -> attention -> proj(+x) -> x1
    for (int w0 = 0; w0 < NWTOT_; w0 += Wc) {
        int wc = NWTOT_ - w0 < Wc ? NWTOT_ - w0 : Wc;
        int rowsA = wc * 64;            // multiple of 128
        ln_kernel<true><<<rowsA / 4, 256, 0, stream>>>(x, ln1_w, ln1_b, bufS, w0 * 64);
        dim3 gq(rowsA / 128, 576 / 192);
        gemm_kernel<EPI_QKV><<<gq, 256, 0, stream>>>(bufS, qkv_wt, qkv_b, bufL, nullptr, 192, 576, 0);
        int nwh = wc * HEADS_;
        attn_kernel<<<(nwh + 3) / 4, 256, 0, stream>>>(bufL, SpreT, bufS, w0, nwh);
        dim3 gp(rowsA / 128, 1);
        gemm_kernel<EPI_PROJ><<<gp, 256, 0, stream>>>(bufS, proj_wt, proj_b, x1, x, 192, 192, w0 * 64);
    }

    // ---- Phase B: fused LN2 -> fc1+gelu -> fc2(+x1), in-place on x1/d_out
    mlp_kernel<<<NTOK_ / 64, 256, 0, stream>>>(x1, ln2_w, ln2_b, fc1_wt, fc1_b,
                                               fc2_wt, fc2_b, x1);
}

// Round 4
// 1123.552 us; speedup vs baseline: 1.1277x; 1.1277x over previous
//
#include <hip/hip_runtime.h>
#include <cstdint>
#include <cstddef>

#define WS_ 8
#define DIM_ 192
#define HEADS_ 6
#define HD_ 32
#define HH_ 56
#define NW_ 7
#define NWIN_ 49
#define LTOK_ 3136
#define NTOK_ 200704
#define NWTOT_ 3136
#define SHIFT_ 4
#define SCALE_ 0.17677669529663687f

typedef unsigned short ushort_t;
typedef __attribute__((ext_vector_type(8))) short short8;
typedef __attribute__((ext_vector_type(4))) short bf16x4;
typedef __attribute__((ext_vector_type(4))) float floatx4;
typedef __attribute__((ext_vector_type(8))) unsigned short ushort8;

__device__ __forceinline__ float b2f(ushort_t u) {
    union { unsigned int i; float f; } c; c.i = ((unsigned int)u) << 16; return c.f;
}
__device__ __forceinline__ ushort_t f2b(float f) {
    union { float f; unsigned int i; } c; c.f = f;
    unsigned int u = c.i;
    unsigned int r = (u + 0x7FFFu + ((u >> 16) & 1u)) >> 16;
    return (ushort_t)r;
}

__device__ __forceinline__ void load_lds16(const void* g, void* l) {
    __builtin_amdgcn_global_load_lds(
        (const __attribute__((address_space(1))) unsigned int*)g,
        (__attribute__((address_space(3))) unsigned int*)l, 16, 0, 0);
}

// global window-token row r (win*64 + n) -> image token index, incl. roll.
__device__ __forceinline__ int win_row_to_img(int r) {
    int win = r >> 6, n = r & 63;
    int b = win / NWIN_, wI = win - b * NWIN_;
    int wh = wI / NW_, wwi = wI - wh * NW_;
    int i = n >> 3, j = n & 7;
    int hh = wh * WS_ + i + SHIFT_; if (hh >= HH_) hh -= HH_;
    int ww = wwi * WS_ + j + SHIFT_; if (ww >= HH_) ww -= HH_;
    return b * LTOK_ + hh * HH_ + ww;
}

// f32 weight [K][N] -> bf16 transposed [N][K]
__global__ void transpose_kernel(const float* __restrict__ in,
                                 ushort_t* __restrict__ out, int K, int N) {
    int id = blockIdx.x * 256 + threadIdx.x;
    if (id >= K * N) return;
    int k = id / N, n = id - k * N;
    out[(size_t)n * K + k] = f2b(in[id]);
}

// Precompute Spre[type][head][q][k] = rpb bias + shift mask.
__global__ void bias_kernel(const float* __restrict__ rpb, float* __restrict__ Spre) {
    int th = blockIdx.x;                 // 0..23 = type*6 + head
    int type = th / HEADS_, head = th - type * HEADS_;
    for (int idx = threadIdx.x; idx < 4096; idx += 256) {
        int q = idx >> 6, k = idx & 63;
        int i1 = q >> 3, j1 = q & 7, i2 = k >> 3, j2 = k & 7;
        int rel = (i1 - i2 + 7) * 15 + (j1 - j2 + 7);
        float v = rpb[rel * HEADS_ + head];
        int rh1 = (type & 2) ? (i1 < 4 ? 1 : 2) : 0;
        int rw1 = (type & 1) ? (j1 < 4 ? 1 : 2) : 0;
        int rh2 = (type & 2) ? (i2 < 4 ? 1 : 2) : 0;
        int rw2 = (type & 1) ? (j2 < 4 ? 1 : 2) : 0;
        if (rh1 != rh2 || rw1 != rw2) v -= 100.0f;
        Spre[(size_t)th * 4096 + idx] = v;
    }
}

// One wave per token; lane covers cols {l, l+64, l+128}. f32 in, bf16 out.
template <bool PERMUTE>
__global__ __launch_bounds__(256) void ln_kernel(const float* __restrict__ xin,
                                                 const float* __restrict__ w,
                                                 const float* __restrict__ bia,
                                                 ushort_t* __restrict__ out,
                                                 int rowOff) {
    int t = blockIdx.x * 4 + (threadIdx.x >> 6);
    int lane = threadIdx.x & 63;
    int src = PERMUTE ? win_row_to_img(rowOff + t) : t;
    const float* xp = xin + (size_t)src * DIM_;
    float v0 = xp[lane];
    float v1 = xp[lane + 64];
    float v2 = xp[lane + 128];
    float s = v0 + v1 + v2;
    float ss = v0 * v0 + v1 * v1 + v2 * v2;
#pragma unroll
    for (int o = 32; o > 0; o >>= 1) {
        s += __shfl_xor(s, o);
        ss += __shfl_xor(ss, o);
    }
    float mu = s * (1.0f / 192.0f);
    float var = ss * (1.0f / 192.0f) - mu * mu;
    float inv = rsqrtf(var + 1e-5f);
    ushort_t* op = out + (size_t)t * DIM_;
    op[lane]       = f2b((v0 - mu) * inv * w[lane]       + bia[lane]);
    op[lane + 64]  = f2b((v1 - mu) * inv * w[lane + 64]  + bia[lane + 64]);
    op[lane + 128] = f2b((v2 - mu) * inv * w[lane + 128] + bia[lane + 128]);
}

#define EPI_STORE 0
#define EPI_GELU 1
#define EPI_PROJ 2
#define EPI_FC2 3
#define EPI_QKV 4

// LDS-staged GEMM: C[M,N] = A[M,K] @ W[K,N] + bias; A,Bt bf16; bias f32.
template <int EPI>
__global__ __launch_bounds__(256) void gemm_kernel(const ushort_t* __restrict__ A,
                                                   const ushort_t* __restrict__ Bt,
                                                   const float* __restrict__ bias,
                                                   void* __restrict__ outv,
                                                   const float* __restrict__ aux,
                                                   int K, int N, int rowOff) {
    __shared__ char smem[40960];  // A: 2 x 8192, B: 2 x 12288

    int tid = threadIdx.x;
    int wave = tid >> 6, lane = tid & 63;
    int quad = lane >> 4, l16 = lane & 15;
    int wave_r = wave >> 1, wave_c = wave & 1;   // 2x2 wave grid
    int row0 = blockIdx.x * 128;
    int n0 = blockIdx.y * 192;

    floatx4 acc[4][6];
#pragma unroll
    for (int rt = 0; rt < 4; ++rt)
#pragma unroll
        for (int ct = 0; ct < 6; ++ct)
#pragma unroll
            for (int e = 0; e < 4; ++e) acc[rt][ct][e] = 0.0f;

    int nk = K >> 5;

    auto stage = [&](int kk, int buf) {
#pragma unroll
        for (int j = 0; j < 2; ++j) {
            int o = (tid + j * 256) * 16;
            int row = o >> 6, kb = o & 63;
            const ushort_t* g = A + (size_t)(row0 + row) * K + kk * 32 + (kb >> 1);
            load_lds16(g, smem + buf * 8192 + o);
        }
#pragma unroll
        for (int j = 0; j < 3; ++j) {
            int o = (tid + j * 256) * 16;
            int row = o >> 6, kb = o & 63;
            const ushort_t* g = Bt + (size_t)(n0 + row) * K + kk * 32 + (kb >> 1);
            load_lds16(g, smem + 16384 + buf * 12288 + o);
        }
    };

    stage(0, 0);
    for (int kk = 0; kk < nk; ++kk) {
        int cur = kk & 1;
        __syncthreads();
        if (kk + 1 < nk) stage(kk + 1, cur ^ 1);

        short8 a[4];
#pragma unroll
        for (int rt = 0; rt < 4; ++rt)
            a[rt] = *(const short8*)(smem + cur * 8192 +
                     ((wave_r * 64 + rt * 16 + l16) * 64 + quad * 16));
#pragma unroll
        for (int ct = 0; ct < 6; ++ct) {
            short8 b = *(const short8*)(smem + 16384 + cur * 12288 +
                        ((wave_c * 96 + ct * 16 + l16) * 64 + quad * 16));
#pragma unroll
            for (int rt = 0; rt < 4; ++rt)
                acc[rt][ct] = __builtin_amdgcn_mfma_f32_16x16x32_bf16(a[rt], b, acc[rt][ct], 0, 0, 0);
        }
    }

#pragma unroll
    for (int ct = 0; ct < 6; ++ct) {
        int c = n0 + wave_c * 96 + ct * 16 + l16;
        float bs = bias[c];
#pragma unroll
        for (int rt = 0; rt < 4; ++rt) {
#pragma unroll
            for (int r = 0; r < 4; ++r) {
                int rr = row0 + wave_r * 64 + rt * 16 + quad * 4 + r;
                float val = acc[rt][ct][r] + bs;
                if (EPI == EPI_STORE) {
                    ((ushort_t*)outv)[(size_t)rr * N + c] = f2b(val);
                } else if (EPI == EPI_QKV) {
                    float sv = (c < DIM_) ? val * SCALE_ : val;
                    ((ushort_t*)outv)[(size_t)rr * N + c] = f2b(sv);
                } else if (EPI == EPI_GELU) {
                    float g = 0.5f * val * (1.0f + erff(val * 0.70710678118654752f));
                    ((ushort_t*)outv)[(size_t)rr * N + c] = f2b(g);
                } else if (EPI == EPI_PROJ) {
                    int dst = win_row_to_img(rowOff + rr);
                    size_t idx = (size_t)dst * DIM_ + c;
                    ((float*)outv)[idx] = val + aux[idx];
                } else {  // EPI_FC2
                    size_t idx = (size_t)rr * DIM_ + c;
                    ((float*)outv)[idx] = val + aux[idx];
                }
            }
        }
    }
}

// MFMA attention: one wave per (window, head). 4 waves/block, wave-private LDS.
__global__ __launch_bounds__(256) void attn_kernel(const ushort_t* __restrict__ qkv,
                                                   const float* __restrict__ Spre,
                                                   ushort_t* __restrict__ aout,
                                                   int win0, int nwh) {
    __shared__ char smem[32768];
    int wave = threadIdx.x >> 6;
    int whid = blockIdx.x * 4 + wave;
    if (whid >= nwh) return;
    int lane = threadIdx.x & 63;
    int l16 = lane & 15, quad = lane >> 4;
    int winl = whid / HEADS_, head = whid - winl * HEADS_;
    int wI = (win0 + winl) % NWIN_;
    int wh = wI / NW_, wwi = wI - wh * NW_;
    int type = ((wh == 6) ? 2 : 0) + ((wwi == 6) ? 1 : 0);

    const ushort_t* qb = qkv + (size_t)(winl * 64) * 576 + head * HD_;

    short8 vfrag[2][2];
#pragma unroll
    for (int kk = 0; kk < 2; ++kk)
#pragma unroll
        for (int dt = 0; dt < 2; ++dt)
#pragma unroll
            for (int e = 0; e < 8; ++e)
                vfrag[dt][kk][e] =
                    (short)qb[(size_t)(kk * 32 + quad * 8 + e) * 576 + 2 * DIM_ + dt * 16 + l16];

    short8 kf[4], qf[4];
#pragma unroll
    for (int t = 0; t < 4; ++t) {
        kf[t] = *(const short8*)(qb + (size_t)(t * 16 + l16) * 576 + DIM_ + quad * 8);
        qf[t] = *(const short8*)(qb + (size_t)(t * 16 + l16) * 576 + quad * 8);
    }

    const float* bp = Spre + (size_t)(type * HEADS_ + head) * 4096;
    floatx4 acc[4][4];
#pragma unroll
    for (int art = 0; art < 4; ++art)
#pragma unroll
        for (int act = 0; act < 4; ++act)
            acc[art][act] = *(const floatx4*)(bp + (act * 16 + l16) * 64 + art * 16 + quad * 4);

#pragma unroll
    for (int art = 0; art < 4; ++art)
#pragma unroll
        for (int act = 0; act < 4; ++act)
            acc[art][act] = __builtin_amdgcn_mfma_f32_16x16x32_bf16(
                kf[art], qf[act], acc[art][act], 0, 0, 0);

    char* pb = smem + wave * 8192;
    int sw = (l16 & 7) << 4;
#pragma unroll
    for (int act = 0; act < 4; ++act) {
        float m = -1e30f;
#pragma unroll
        for (int art = 0; art < 4; ++art)
#pragma unroll
            for (int r = 0; r < 4; ++r) m = fmaxf(m, acc[art][act][r]);
        m = fmaxf(m, __shfl_xor(m, 16));
        m = fmaxf(m, __shfl_xor(m, 32));
        float s = 0.0f;
#pragma unroll
        for (int art = 0; art < 4; ++art)
#pragma unroll
            for (int r = 0; r < 4; ++r) {
                float e = __expf(acc[art][act][r] - m);
                acc[art][act][r] = e;
                s += e;
            }
        s += __shfl_xor(s, 16);
        s += __shfl_xor(s, 32);
        float inv = 1.0f / s;
        int q = act * 16 + l16;
        char* rowp = pb + q * 128;
#pragma unroll
        for (int art = 0; art < 4; ++art) {
            bf16x4 pk4;
#pragma unroll
            for (int r = 0; r < 4; ++r) pk4[r] = (short)f2b(acc[art][act][r] * inv);
            *(bf16x4*)(rowp + ((art * 32 + quad * 8) ^ sw)) = pk4;
        }
    }

    floatx4 accO[4][2];
#pragma unroll
    for (int ot = 0; ot < 4; ++ot)
#pragma unroll
        for (int dt = 0; dt < 2; ++dt)
#pragma unroll
            for (int e = 0; e < 4; ++e) accO[ot][dt][e] = 0.0f;
#pragma unroll
    for (int kk = 0; kk < 2; ++kk) {
        short8 pa[4];
#pragma unroll
        for (int ot = 0; ot < 4; ++ot)
            pa[ot] = *(const short8*)(pb + (ot * 16 + l16) * 128 +
                                      ((kk * 64 + quad * 16) ^ sw));
#pragma unroll
        for (int dt = 0; dt < 2; ++dt)
#pragma unroll
            for (int ot = 0; ot < 4; ++ot)
                accO[ot][dt] = __builtin_amdgcn_mfma_f32_16x16x32_bf16(
                    pa[ot], vfrag[dt][kk], accO[ot][dt], 0, 0, 0);
    }

    ushort_t* op = aout + (size_t)(winl * 64) * DIM_ + head * HD_;
#pragma unroll
    for (int ot = 0; ot < 4; ++ot)
#pragma unroll
        for (int dt = 0; dt < 2; ++dt)
#pragma unroll
            for (int r = 0; r < 4; ++r)
                op[(size_t)(ot * 16 + quad * 4 + r) * DIM_ + dt * 16 + l16] =
                    f2b(accO[ot][dt][r]);
}

extern "C" void kernel_launch(void* const* d_in, const int* in_sizes, int n_in,
                              void* d_out, int out_size, void* d_ws, size_t ws_size,
                              hipStream_t stream) {
    const float* x      = (const float*)d_in[0];
    const float* ln1_w  = (const float*)d_in[1];
    const float* ln1_b  = (const float*)d_in[2];
    const float* qkv_w  = (const float*)d_in[3];
    const float* qkv_b  = (const float*)d_in[4];
    const float* proj_w = (const float*)d_in[5];
    const float* proj_b = (const float*)d_in[6];
    const float* rpb    = (const float*)d_in[7];
    const float* ln2_w  = (const float*)d_in[8];
    const float* ln2_b  = (const float*)d_in[9];
    const float* fc1_w  = (const float*)d_in[10];
    const float* fc1_b  = (const float*)d_in[11];
    const float* fc2_w  = (const float*)d_in[12];
    const float* fc2_b  = (const float*)d_in[13];

    char* ws = (char*)d_ws;
    size_t off = 0;
    auto alloc = [&](size_t bytes) -> void* {
        void* p = ws + off;
        off += (bytes + 255) & ~(size_t)255;
        return p;
    };
    ushort_t* qkv_wt  = (ushort_t*)alloc((size_t)576 * 192 * 2);
    ushort_t* proj_wt = (ushort_t*)alloc((size_t)192 * 192 * 2);
    ushort_t* fc1_wt  = (ushort_t*)alloc((size_t)768 * 192 * 2);
    ushort_t* fc2_wt  = (ushort_t*)alloc((size_t)192 * 768 * 2);
    float*    SpreT   = (float*)alloc((size_t)4 * HEADS_ * 4096 * sizeof(float));

    // x1 lives in d_out (f32; fully written by proj scatter before any read).
    float* x1 = (float*)d_out;

    size_t budget = (ws_size > off + 4096) ? (ws_size - off - 4096) : 0;
    long rows = (long)(budget / 1920);
    rows = (rows / 128) * 128;
    if (rows < 128) rows = 128;
    if (rows > NTOK_) rows = NTOK_;
    // Cap chunk so per-chunk working set (bufS 18.9MB + bufL 75.5MB + x1
    // slice 37.7MB) stays Infinity-Cache-resident: intermediates (qkv, h)
    // then never round-trip through HBM between pipeline kernels.
    if (rows > 49152) rows = 49152;
    int chunkRows = (int)rows;
    int Wc = chunkRows / 64;            // even
    if (Wc > NWTOT_) Wc = NWTOT_;

    ushort_t* bufS = (ushort_t*)alloc((size_t)chunkRows * 192 * 2);  // xw / attn_out / xn2
    ushort_t* bufL = (ushort_t*)alloc((size_t)chunkRows * 768 * 2);  // qkv / h
    (void)n_in; (void)in_sizes; (void)out_size;

    transpose_kernel<<<(192 * 576 + 255) / 256, 256, 0, stream>>>(qkv_w, qkv_wt, 192, 576);
    transpose_kernel<<<(192 * 192 + 255) / 256, 256, 0, stream>>>(proj_w, proj_wt, 192, 192);
    transpose_kernel<<<(192 * 768 + 255) / 256, 256, 0, stream>>>(fc1_w, fc1_wt, 192, 768);
    transpose_kernel<<<(768 * 192 + 255) / 256, 256, 0, stream>>>(fc2_w, fc2_wt, 768, 192);
    bias_kernel<<<4 * HEADS_, 256, 0, stream>>>(rpb, SpreT);

    // ---- Phase A: LN1+roll+partition -> qkv(+scale q) -> attention -> proj(+x) -> x1
    for (int w0 = 0; w0 < NWTOT_; w0 += Wc) {
        int wc = NWTOT_ - w0 < Wc ? NWTOT_ - w0 : Wc;
        int rowsA = wc * 64;            // multiple of 128
        ln_kernel<true><<<rowsA / 4, 256, 0, stream>>>(x, ln1_w, ln1_b, bufS, w0 * 64);
        dim3 gq(rowsA / 128, 576 / 192);
        gemm_kernel<EPI_QKV><<<gq, 256, 0, stream>>>(bufS, qkv_wt, qkv_b, bufL, nullptr, 192, 576, 0);
        int nwh = wc * HEADS_;
        attn_kernel<<<(nwh + 3) / 4, 256, 0, stream>>>(bufL, SpreT, bufS, w0, nwh);
        dim3 gp(rowsA / 128, 1);
        gemm_kernel<EPI_PROJ><<<gp, 256, 0, stream>>>(bufS, proj_wt, proj_b, x1, x, 192, 192, w0 * 64);
    }

    // ---- Phase B: LN2 -> fc1+gelu -> fc2(+x1) -> d_out
    for (int t0 = 0; t0 < NTOK_; t0 += chunkRows) {
        int tc = NTOK_ - t0 < chunkRows ? NTOK_ - t0 : chunkRows;
        ln_kernel<false><<<tc / 4, 256, 0, stream>>>(x1 + (size_t)t0 * 192, ln2_w, ln2_b, bufS, 0);
        dim3 g1(tc / 128, 768 / 192);
        gemm_kernel<EPI_GELU><<<g1, 256, 0, stream>>>(bufS, fc1_wt, fc1_b, bufL, nullptr, 192, 768, 0);
        dim3 g2(tc / 128, 1);
        gemm_kernel<EPI_FC2><<<g2, 256, 0, stream>>>(bufL, fc2_wt, fc2_b,
                                                     x1 + (size_t)t0 * 192,
                                                     x1 + (size_t)t0 * 192, 768, 192, 0);
    }
}

// Round 5
// 1018.081 us; speedup vs baseline: 1.2445x; 1.1036x over previous
//
#include <hip/hip_runtime.h>
#include <cstdint>
#include <cstddef>

#define WS_ 8
#define DIM_ 192
#define HEADS_ 6
#define HD_ 32
#define HH_ 56
#define NW_ 7
#define NWIN_ 49
#define LTOK_ 3136
#define NTOK_ 200704
#define NWTOT_ 3136
#define SHIFT_ 4
#define SCALE_ 0.17677669529663687f

typedef unsigned short ushort_t;
typedef __attribute__((ext_vector_type(8))) short short8;
typedef __attribute__((ext_vector_type(4))) short bf16x4;
typedef __attribute__((ext_vector_type(4))) float floatx4;
typedef __attribute__((ext_vector_type(8))) unsigned short ushort8;

__device__ __forceinline__ float b2f(ushort_t u) {
    union { unsigned int i; float f; } c; c.i = ((unsigned int)u) << 16; return c.f;
}
__device__ __forceinline__ ushort_t f2b(float f) {
    union { float f; unsigned int i; } c; c.f = f;
    unsigned int u = c.i;
    unsigned int r = (u + 0x7FFFu + ((u >> 16) & 1u)) >> 16;
    return (ushort_t)r;
}

__device__ __forceinline__ void load_lds16(const void* g, void* l) {
    __builtin_amdgcn_global_load_lds(
        (const __attribute__((address_space(1))) unsigned int*)g,
        (__attribute__((address_space(3))) unsigned int*)l, 16, 0, 0);
}

// Bank-conflict swizzle for 64B-row LDS slabs (bijective):
//   addr = (row<<6) ^ (q<<4) ^ ((row&7)<<4)     [q = 16B-slice in row]
// Inverse (given linear LDS byte offset o within slab):
//   row = ((o>>7)<<1) | (((o>>6) ^ (o>>8)) & 1);  q = ((o>>4)&3) ^ (row&3)
__device__ __forceinline__ int swz_row(int o) {
    return ((o >> 7) << 1) | (((o >> 6) ^ (o >> 8)) & 1);
}
__device__ __forceinline__ int swz_rd(int row, int quad) {
    return (row << 6) ^ (quad << 4) ^ ((row & 7) << 4);
}

// global window-token row r (win*64 + n) -> image token index, incl. roll.
__device__ __forceinline__ int win_row_to_img(int r) {
    int win = r >> 6, n = r & 63;
    int b = win / NWIN_, wI = win - b * NWIN_;
    int wh = wI / NW_, wwi = wI - wh * NW_;
    int i = n >> 3, j = n & 7;
    int hh = wh * WS_ + i + SHIFT_; if (hh >= HH_) hh -= HH_;
    int ww = wwi * WS_ + j + SHIFT_; if (ww >= HH_) ww -= HH_;
    return b * LTOK_ + hh * HH_ + ww;
}

// f32 weight [K][N] -> bf16 transposed [N][K]
__global__ void transpose_kernel(const float* __restrict__ in,
                                 ushort_t* __restrict__ out, int K, int N) {
    int id = blockIdx.x * 256 + threadIdx.x;
    if (id >= K * N) return;
    int k = id / N, n = id - k * N;
    out[(size_t)n * K + k] = f2b(in[id]);
}

// Precompute Spre[type][head][q][k] = rpb bias + shift mask.
__global__ void bias_kernel(const float* __restrict__ rpb, float* __restrict__ Spre) {
    int th = blockIdx.x;                 // 0..23 = type*6 + head
    int type = th / HEADS_, head = th - type * HEADS_;
    for (int idx = threadIdx.x; idx < 4096; idx += 256) {
        int q = idx >> 6, k = idx & 63;
        int i1 = q >> 3, j1 = q & 7, i2 = k >> 3, j2 = k & 7;
        int rel = (i1 - i2 + 7) * 15 + (j1 - j2 + 7);
        float v = rpb[rel * HEADS_ + head];
        int rh1 = (type & 2) ? (i1 < 4 ? 1 : 2) : 0;
        int rw1 = (type & 1) ? (j1 < 4 ? 1 : 2) : 0;
        int rh2 = (type & 2) ? (i2 < 4 ? 1 : 2) : 0;
        int rw2 = (type & 1) ? (j2 < 4 ? 1 : 2) : 0;
        if (rh1 != rh2 || rw1 != rw2) v -= 100.0f;
        Spre[(size_t)th * 4096 + idx] = v;
    }
}

// One wave per token; lane covers cols {l, l+64, l+128}. f32 in, bf16 out.
template <bool PERMUTE>
__global__ __launch_bounds__(256) void ln_kernel(const float* __restrict__ xin,
                                                 const float* __restrict__ w,
                                                 const float* __restrict__ bia,
                                                 ushort_t* __restrict__ out,
                                                 int rowOff) {
    int t = blockIdx.x * 4 + (threadIdx.x >> 6);
    int lane = threadIdx.x & 63;
    int src = PERMUTE ? win_row_to_img(rowOff + t) : t;
    const float* xp = xin + (size_t)src * DIM_;
    float v0 = xp[lane];
    float v1 = xp[lane + 64];
    float v2 = xp[lane + 128];
    float s = v0 + v1 + v2;
    float ss = v0 * v0 + v1 * v1 + v2 * v2;
#pragma unroll
    for (int o = 32; o > 0; o >>= 1) {
        s += __shfl_xor(s, o);
        ss += __shfl_xor(ss, o);
    }
    float mu = s * (1.0f / 192.0f);
    float var = ss * (1.0f / 192.0f) - mu * mu;
    float inv = rsqrtf(var + 1e-5f);
    ushort_t* op = out + (size_t)t * DIM_;
    op[lane]       = f2b((v0 - mu) * inv * w[lane]       + bia[lane]);
    op[lane + 64]  = f2b((v1 - mu) * inv * w[lane + 64]  + bia[lane + 64]);
    op[lane + 128] = f2b((v2 - mu) * inv * w[lane + 128] + bia[lane + 128]);
}

#define EPI_STORE 0
#define EPI_GELU 1
#define EPI_PROJ 2
#define EPI_FC2 3
#define EPI_QKV 4

// LDS-staged GEMM: C[M,N] = A[M,K] @ W[K,N] + bias; A,Bt bf16; bias f32.
// LDS slabs swizzled (pre-swizzled global src + swizzled reads).
template <int EPI>
__global__ __launch_bounds__(256) void gemm_kernel(const ushort_t* __restrict__ A,
                                                   const ushort_t* __restrict__ Bt,
                                                   const float* __restrict__ bias,
                                                   void* __restrict__ outv,
                                                   const float* __restrict__ aux,
                                                   int K, int N, int rowOff) {
    __shared__ char smem[40960];  // A: 2 x 8192, B: 2 x 12288

    int tid = threadIdx.x;
    int wave = tid >> 6, lane = tid & 63;
    int quad = lane >> 4, l16 = lane & 15;
    int wave_r = wave >> 1, wave_c = wave & 1;   // 2x2 wave grid
    int row0 = blockIdx.x * 128;
    int n0 = blockIdx.y * 192;

    floatx4 acc[4][6];
#pragma unroll
    for (int rt = 0; rt < 4; ++rt)
#pragma unroll
        for (int ct = 0; ct < 6; ++ct)
#pragma unroll
            for (int e = 0; e < 4; ++e) acc[rt][ct][e] = 0.0f;

    int nk = K >> 5;

    auto stage = [&](int kk, int buf) {
#pragma unroll
        for (int j = 0; j < 2; ++j) {
            int o = (tid + j * 256) * 16;
            int row = swz_row(o);
            int q = ((o >> 4) & 3) ^ (row & 3);
            const ushort_t* g = A + (size_t)(row0 + row) * K + kk * 32 + q * 8;
            load_lds16(g, smem + buf * 8192 + o);
        }
#pragma unroll
        for (int j = 0; j < 3; ++j) {
            int o = (tid + j * 256) * 16;
            int row = swz_row(o);
            int q = ((o >> 4) & 3) ^ (row & 3);
            const ushort_t* g = Bt + (size_t)(n0 + row) * K + kk * 32 + q * 8;
            load_lds16(g, smem + 16384 + buf * 12288 + o);
        }
    };

    stage(0, 0);
    for (int kk = 0; kk < nk; ++kk) {
        int cur = kk & 1;
        __syncthreads();
        if (kk + 1 < nk) stage(kk + 1, cur ^ 1);

        short8 a[4];
#pragma unroll
        for (int rt = 0; rt < 4; ++rt) {
            int ar = wave_r * 64 + rt * 16 + l16;
            a[rt] = *(const short8*)(smem + cur * 8192 + swz_rd(ar, quad));
        }
#pragma unroll
        for (int ct = 0; ct < 6; ++ct) {
            int br = wave_c * 96 + ct * 16 + l16;
            short8 b = *(const short8*)(smem + 16384 + cur * 12288 + swz_rd(br, quad));
#pragma unroll
            for (int rt = 0; rt < 4; ++rt)
                acc[rt][ct] = __builtin_amdgcn_mfma_f32_16x16x32_bf16(a[rt], b, acc[rt][ct], 0, 0, 0);
        }
    }

#pragma unroll
    for (int ct = 0; ct < 6; ++ct) {
        int c = n0 + wave_c * 96 + ct * 16 + l16;
        float bs = bias[c];
#pragma unroll
        for (int rt = 0; rt < 4; ++rt) {
#pragma unroll
            for (int r = 0; r < 4; ++r) {
                int rr = row0 + wave_r * 64 + rt * 16 + quad * 4 + r;
                float val = acc[rt][ct][r] + bs;
                if (EPI == EPI_STORE) {
                    ((ushort_t*)outv)[(size_t)rr * N + c] = f2b(val);
                } else if (EPI == EPI_QKV) {
                    float sv = (c < DIM_) ? val * SCALE_ : val;
                    ((ushort_t*)outv)[(size_t)rr * N + c] = f2b(sv);
                } else if (EPI == EPI_GELU) {
                    float g = 0.5f * val * (1.0f + erff(val * 0.70710678118654752f));
                    ((ushort_t*)outv)[(size_t)rr * N + c] = f2b(g);
                } else if (EPI == EPI_PROJ) {
                    int dst = win_row_to_img(rowOff + rr);
                    size_t idx = (size_t)dst * DIM_ + c;
                    ((float*)outv)[idx] = val + aux[idx];
                } else {  // EPI_FC2
                    size_t idx = (size_t)rr * DIM_ + c;
                    ((float*)outv)[idx] = val + aux[idx];
                }
            }
        }
    }
}

// MFMA attention: one wave per (window, head). 4 waves/block, wave-private LDS.
__global__ __launch_bounds__(256) void attn_kernel(const ushort_t* __restrict__ qkv,
                                                   const float* __restrict__ Spre,
                                                   ushort_t* __restrict__ aout,
                                                   int win0, int nwh) {
    __shared__ char smem[32768];
    int wave = threadIdx.x >> 6;
    int whid = blockIdx.x * 4 + wave;
    if (whid >= nwh) return;
    int lane = threadIdx.x & 63;
    int l16 = lane & 15, quad = lane >> 4;
    int winl = whid / HEADS_, head = whid - winl * HEADS_;
    int wI = (win0 + winl) % NWIN_;
    int wh = wI / NW_, wwi = wI - wh * NW_;
    int type = ((wh == 6) ? 2 : 0) + ((wwi == 6) ? 1 : 0);

    const ushort_t* qb = qkv + (size_t)(winl * 64) * 576 + head * HD_;

    short8 vfrag[2][2];
#pragma unroll
    for (int kk = 0; kk < 2; ++kk)
#pragma unroll
        for (int dt = 0; dt < 2; ++dt)
#pragma unroll
            for (int e = 0; e < 8; ++e)
                vfrag[dt][kk][e] =
                    (short)qb[(size_t)(kk * 32 + quad * 8 + e) * 576 + 2 * DIM_ + dt * 16 + l16];

    short8 kf[4], qf[4];
#pragma unroll
    for (int t = 0; t < 4; ++t) {
        kf[t] = *(const short8*)(qb + (size_t)(t * 16 + l16) * 576 + DIM_ + quad * 8);
        qf[t] = *(const short8*)(qb + (size_t)(t * 16 + l16) * 576 + quad * 8);
    }

    const float* bp = Spre + (size_t)(type * HEADS_ + head) * 4096;
    floatx4 acc[4][4];
#pragma unroll
    for (int art = 0; art < 4; ++art)
#pragma unroll
        for (int act = 0; act < 4; ++act)
            acc[art][act] = *(const floatx4*)(bp + (act * 16 + l16) * 64 + art * 16 + quad * 4);

#pragma unroll
    for (int art = 0; art < 4; ++art)
#pragma unroll
        for (int act = 0; act < 4; ++act)
            acc[art][act] = __builtin_amdgcn_mfma_f32_16x16x32_bf16(
                kf[art], qf[act], acc[art][act], 0, 0, 0);

    char* pb = smem + wave * 8192;
    int sw = (l16 & 7) << 4;
#pragma unroll
    for (int act = 0; act < 4; ++act) {
        float m = -1e30f;
#pragma unroll
        for (int art = 0; art < 4; ++art)
#pragma unroll
            for (int r = 0; r < 4; ++r) m = fmaxf(m, acc[art][act][r]);
        m = fmaxf(m, __shfl_xor(m, 16));
        m = fmaxf(m, __shfl_xor(m, 32));
        float s = 0.0f;
#pragma unroll
        for (int art = 0; art < 4; ++art)
#pragma unroll
            for (int r = 0; r < 4; ++r) {
                float e = __expf(acc[art][act][r] - m);
                acc[art][act][r] = e;
                s += e;
            }
        s += __shfl_xor(s, 16);
        s += __shfl_xor(s, 32);
        float inv = 1.0f / s;
        int q = act * 16 + l16;
        char* rowp = pb + q * 128;
#pragma unroll
        for (int art = 0; art < 4; ++art) {
            bf16x4 pk4;
#pragma unroll
            for (int r = 0; r < 4; ++r) pk4[r] = (short)f2b(acc[art][act][r] * inv);
            *(bf16x4*)(rowp + ((art * 32 + quad * 8) ^ sw)) = pk4;
        }
    }

    floatx4 accO[4][2];
#pragma unroll
    for (int ot = 0; ot < 4; ++ot)
#pragma unroll
        for (int dt = 0; dt < 2; ++dt)
#pragma unroll
            for (int e = 0; e < 4; ++e) accO[ot][dt][e] = 0.0f;
#pragma unroll
    for (int kk = 0; kk < 2; ++kk) {
        short8 pa[4];
#pragma unroll
        for (int ot = 0; ot < 4; ++ot)
            pa[ot] = *(const short8*)(pb + (ot * 16 + l16) * 128 +
                                      ((kk * 64 + quad * 16) ^ sw));
#pragma unroll
        for (int dt = 0; dt < 2; ++dt)
#pragma unroll
            for (int ot = 0; ot < 4; ++ot)
                accO[ot][dt] = __builtin_amdgcn_mfma_f32_16x16x32_bf16(
                    pa[ot], vfrag[dt][kk], accO[ot][dt], 0, 0, 0);
    }

    ushort_t* op = aout + (size_t)(winl * 64) * DIM_ + head * HD_;
#pragma unroll
    for (int ot = 0; ot < 4; ++ot)
#pragma unroll
        for (int dt = 0; dt < 2; ++dt)
#pragma unroll
            for (int r = 0; r < 4; ++r)
                op[(size_t)(ot * 16 + quad * 4 + r) * DIM_ + dt * 16 + l16] =
                    f2b(accO[ot][dt][r]);
}

// Fused fc1+gelu+fc2+residual. One block = 64 tokens, 4 waves.
// h computed in six 128-col groups; only current group's h-tile [64][128]
// lives in LDS (16 KB). Waves partition N (fc1: 32 cols each; fc2: 48 cols
// each) so each weight fragment is fetched exactly once per block (L2-hot).
// A-tile (xn2) staged once via global_load_lds into 6 swizzled 64B-row
// slabs. fc2 accumulates in registers across groups (48 VGPR/lane).
__global__ __launch_bounds__(256) void mlp_kernel(const ushort_t* __restrict__ xn,
                                                  const float* __restrict__ x1r,
                                                  const ushort_t* __restrict__ w1t,
                                                  const float* __restrict__ b1,
                                                  const ushort_t* __restrict__ w2t,
                                                  const float* __restrict__ b2,
                                                  float* __restrict__ out) {
    __shared__ char smem[40960];
    char* As = smem;            // 6 slabs x 4096 B  ([64 rows][64 B k-slice])
    char* Hs = smem + 24576;    // 4 slabs x 4096 B
    int tid = threadIdx.x;
    int wave = tid >> 6, lane = tid & 63;
    int quad = lane >> 4, l16 = lane & 15;
    int row0 = blockIdx.x * 64;

    // stage A tile [64][192] bf16 as 6 swizzled slabs (linear LDS dest,
    // pre-swizzled global src)
#pragma unroll
    for (int j = 0; j < 6; ++j) {
        int o = (j * 256 + tid) * 16;
        int slab = o >> 12;
        int os = o & 4095;
        int row = swz_row(os);
        int q = ((os >> 4) & 3) ^ (row & 3);
        const ushort_t* g = xn + (size_t)(row0 + row) * DIM_ + slab * 32 + q * 8;
        load_lds16(g, As + o);
    }

    floatx4 acc2[4][3];
#pragma unroll
    for (int rt = 0; rt < 4; ++rt)
#pragma unroll
        for (int ct = 0; ct < 3; ++ct)
#pragma unroll
            for (int e = 0; e < 4; ++e) acc2[rt][ct][e] = 0.0f;

    __syncthreads();   // A staged (drains vmcnt)

#pragma unroll 1
    for (int g = 0; g < 6; ++g) {
        // ---- fc1: this wave's 32 cols of group g (N-partitioned)
        floatx4 acc1[4][2];
#pragma unroll
        for (int rt = 0; rt < 4; ++rt)
#pragma unroll
            for (int ct = 0; ct < 2; ++ct)
#pragma unroll
                for (int e = 0; e < 4; ++e) acc1[rt][ct][e] = 0.0f;
#pragma unroll
        for (int s = 0; s < 6; ++s) {
            short8 a[4];
#pragma unroll
            for (int rt = 0; rt < 4; ++rt) {
                int ar = rt * 16 + l16;
                a[rt] = *(const short8*)(As + s * 4096 + swz_rd(ar, quad));
            }
#pragma unroll
            for (int ct = 0; ct < 2; ++ct) {
                int n = g * 128 + wave * 32 + ct * 16 + l16;
                short8 b = *(const short8*)(w1t + (size_t)n * 192 + s * 32 + quad * 8);
#pragma unroll
                for (int rt = 0; rt < 4; ++rt)
                    acc1[rt][ct] = __builtin_amdgcn_mfma_f32_16x16x32_bf16(
                        a[rt], b, acc1[rt][ct], 0, 0, 0);
            }
        }
        // ---- gelu -> bf16 -> Hs (swizzled; slab = wave since cols 32-contig)
#pragma unroll
        for (int ct = 0; ct < 2; ++ct) {
            int cl = wave * 32 + ct * 16 + l16;      // within-group col 0..127
            float bs = b1[g * 128 + cl];
            int kq = (cl & 31) >> 3;
            int kb = (cl & 7) * 2;
#pragma unroll
            for (int rt = 0; rt < 4; ++rt) {
#pragma unroll
                for (int r = 0; r < 4; ++r) {
                    int R = rt * 16 + quad * 4 + r;
                    float val = acc1[rt][ct][r] + bs;
                    float gg = 0.5f * val * (1.0f + erff(val * 0.70710678118654752f));
                    *(ushort_t*)(Hs + wave * 4096 + swz_rd(R, kq) + kb) = f2b(gg);
                }
            }
        }
        __syncthreads();   // h group ready
        // ---- fc2 partial: K-slice g*128..+127; wave owns 48 output cols
#pragma unroll
        for (int s2 = 0; s2 < 4; ++s2) {
            short8 a2[4];
#pragma unroll
            for (int rt = 0; rt < 4; ++rt) {
                int ar = rt * 16 + l16;
                a2[rt] = *(const short8*)(Hs + s2 * 4096 + swz_rd(ar, quad));
            }
#pragma unroll
            for (int ct = 0; ct < 3; ++ct) {
                int n2 = wave * 48 + ct * 16 + l16;
                short8 b2v = *(const short8*)(w2t + (size_t)n2 * 768 +
                                              g * 128 + s2 * 32 + quad * 8);
#pragma unroll
                for (int rt = 0; rt < 4; ++rt)
                    acc2[rt][ct] = __builtin_amdgcn_mfma_f32_16x16x32_bf16(
                        a2[rt], b2v, acc2[rt][ct], 0, 0, 0);
            }
        }
        __syncthreads();   // Hs free for next group
    }

    // ---- epilogue: + bias + residual, f32 in-place
#pragma unroll
    for (int ct = 0; ct < 3; ++ct) {
        int c = wave * 48 + ct * 16 + l16;
        float bs = b2[c];
#pragma unroll
        for (int rt = 0; rt < 4; ++rt) {
#pragma unroll
            for (int r = 0; r < 4; ++r) {
                int rr = row0 + rt * 16 + quad * 4 + r;
                size_t idx = (size_t)rr * DIM_ + c;
                out[idx] = acc2[rt][ct][r] + bs + x1r[idx];
            }
        }
    }
}

extern "C" void kernel_launch(void* const* d_in, const int* in_sizes, int n_in,
                              void* d_out, int out_size, void* d_ws, size_t ws_size,
                              hipStream_t stream) {
    const float* x      = (const float*)d_in[0];
    const float* ln1_w  = (const float*)d_in[1];
    const float* ln1_b  = (const float*)d_in[2];
    const float* qkv_w  = (const float*)d_in[3];
    const float* qkv_b  = (const float*)d_in[4];
    const float* proj_w = (const float*)d_in[5];
    const float* proj_b = (const float*)d_in[6];
    const float* rpb    = (const float*)d_in[7];
    const float* ln2_w  = (const float*)d_in[8];
    const float* ln2_b  = (const float*)d_in[9];
    const float* fc1_w  = (const float*)d_in[10];
    const float* fc1_b  = (const float*)d_in[11];
    const float* fc2_w  = (const float*)d_in[12];
    const float* fc2_b  = (const float*)d_in[13];

    char* ws = (char*)d_ws;
    size_t off = 0;
    auto alloc = [&](size_t bytes) -> void* {
        void* p = ws + off;
        off += (bytes + 255) & ~(size_t)255;
        return p;
    };
    ushort_t* qkv_wt  = (ushort_t*)alloc((size_t)576 * 192 * 2);
    ushort_t* proj_wt = (ushort_t*)alloc((size_t)192 * 192 * 2);
    ushort_t* fc1_wt  = (ushort_t*)alloc((size_t)768 * 192 * 2);
    ushort_t* fc2_wt  = (ushort_t*)alloc((size_t)192 * 768 * 2);
    float*    SpreT   = (float*)alloc((size_t)4 * HEADS_ * 4096 * sizeof(float));

    // x1 lives in d_out (f32; fully written by proj scatter before any read).
    float* x1 = (float*)d_out;

    size_t budget = (ws_size > off + 4096) ? (ws_size - off - 4096) : 0;
    long rows = (long)(budget / 1920);
    rows = (rows / 128) * 128;
    if (rows < 128) rows = 128;
    if (rows > NTOK_) rows = NTOK_;
    int chunkRows = (int)rows;
    int Wc = chunkRows / 64;            // even
    if (Wc > NWTOT_) Wc = NWTOT_;

    ushort_t* bufS = (ushort_t*)alloc((size_t)chunkRows * 192 * 2);  // xw / attn_out / xn2
    ushort_t* bufL = (ushort_t*)alloc((size_t)chunkRows * 768 * 2);  // qkv
    (void)n_in; (void)in_sizes; (void)out_size;

    transpose_kernel<<<(192 * 576 + 255) / 256, 256, 0, stream>>>(qkv_w, qkv_wt, 192, 576);
    transpose_kernel<<<(192 * 192 + 255) / 256, 256, 0, stream>>>(proj_w, proj_wt, 192, 192);
    transpose_kernel<<<(192 * 768 + 255) / 256, 256, 0, stream>>>(fc1_w, fc1_wt, 192, 768);
    transpose_kernel<<<(768 * 192 + 255) / 256, 256, 0, stream>>>(fc2_w, fc2_wt, 768, 192);
    bias_kernel<<<4 * HEADS_, 256, 0, stream>>>(rpb, SpreT);

    // ---- Phase A: LN1+roll+partition -> qkv(+scale q) -> attention -> proj(+x) -> x1
    for (int w0 = 0; w0 < NWTOT_; w0 += Wc) {
        int wc = NWTOT_ - w0 < Wc ? NWTOT_ - w0 : Wc;
        int rowsA = wc * 64;            // multiple of 128
        ln_kernel<true><<<rowsA / 4, 256, 0, stream>>>(x, ln1_w, ln1_b, bufS, w0 * 64);
        dim3 gq(rowsA / 128, 576 / 192);
        gemm_kernel<EPI_QKV><<<gq, 256, 0, stream>>>(bufS, qkv_wt, qkv_b, bufL, nullptr, 192, 576, 0);
        int nwh = wc * HEADS_;
        attn_kernel<<<(nwh + 3) / 4, 256, 0, stream>>>(bufL, SpreT, bufS, w0, nwh);
        dim3 gp(rowsA / 128, 1);
        gemm_kernel<EPI_PROJ><<<gp, 256, 0, stream>>>(bufS, proj_wt, proj_b, x1, x, 192, 192, w0 * 64);
    }

    // ---- Phase B: LN2 -> fused fc1+gelu+fc2+residual (in-place on x1/d_out)
    for (int t0 = 0; t0 < NTOK_; t0 += chunkRows) {
        int tc = NTOK_ - t0 < chunkRows ? NTOK_ - t0 : chunkRows;
        ln_kernel<false><<<tc / 4, 256, 0, stream>>>(x1 + (size_t)t0 * 192, ln2_w, ln2_b, bufS, 0);
        mlp_kernel<<<tc / 64, 256, 0, stream>>>(bufS, x1 + (size_t)t0 * 192,
                                                fc1_wt, fc1_b, fc2_wt, fc2_b,
                                                x1 + (size_t)t0 * 192);
    }
}